// Round 3
// baseline (12120.354 us; speedup 1.0000x reference)
//
#include <hip/hip_runtime.h>
#include <math.h>

#define SS   256
#define BB   128
#define INN  256
#define HH   256
#define NG   1024   // 4*H
#define NL   2
#define EPSV 1e-5f

__device__ __forceinline__ float sum4(float4 v)   { return v.x + v.y + v.z + v.w; }
__device__ __forceinline__ float sumsq4(float4 v) { return v.x*v.x + v.y*v.y + v.z*v.z + v.w*v.w; }
__device__ __forceinline__ float fast_sigmoid(float x) { return 1.0f / (1.0f + __expf(-x)); }
__device__ __forceinline__ float fast_tanh(float x) {
  float t = __expf(-2.0f * fabsf(x));
  float r = (1.0f - t) / (1.0f + t);
  return copysignf(r, x);
}

__global__ void init_state(const float* __restrict__ h0, const float* __restrict__ c0,
                           float* __restrict__ hs, float* __restrict__ cs, int n) {
  int i = blockIdx.x * blockDim.x + threadIdx.x;
  if (i < n) { hs[i] = h0[i]; cs[i] = c0[i]; }
}

// C[M x NG] = A[M x 256] * W[256 x NG]. Raw output (LN fused later). M = nt*BB per chunk.
// 128x128 tile, 256 threads, 8x8 micro-tile, K-slice 16.
__global__ __launch_bounds__(256) void gemm_gx(const float* __restrict__ A,
                                               const float* __restrict__ W,
                                               float* __restrict__ C) {
  __shared__ __align__(16) float As[16][132];   // [k][m], 132*4B row stride (16B-aligned)
  __shared__ __align__(16) float Bs[16][132];   // [k][n]
  const int tid = threadIdx.x;
  const int bn  = blockIdx.x * 128;
  const int bm  = blockIdx.y * 128;
  const int tx  = tid & 15;          // output col group (8 cols)
  const int ty  = tid >> 4;          // output row group (8 rows)
  const int am  = tid >> 1;          // A row in tile (0..127)
  const int ac  = (tid & 1) << 3;    // A k offset (0 or 8)
  const int br  = tid >> 4;          // B k row (0..15)
  const int bc  = (tid & 15) << 2;   // B col (0,4,...,60)

  float acc[8][8] = {};
  for (int k0 = 0; k0 < INN; k0 += 16) {
    const float4 a0 = *(const float4*)&A[(size_t)(bm + am) * INN + k0 + ac];
    const float4 a1 = *(const float4*)&A[(size_t)(bm + am) * INN + k0 + ac + 4];
    const float4 b0 = *(const float4*)&W[(size_t)(k0 + br) * NG + bn + bc];
    const float4 b1 = *(const float4*)&W[(size_t)(k0 + br) * NG + bn + bc + 64];
    __syncthreads();
    As[ac + 0][am] = a0.x; As[ac + 1][am] = a0.y; As[ac + 2][am] = a0.z; As[ac + 3][am] = a0.w;
    As[ac + 4][am] = a1.x; As[ac + 5][am] = a1.y; As[ac + 6][am] = a1.z; As[ac + 7][am] = a1.w;
    *(float4*)&Bs[br][bc]      = b0;
    *(float4*)&Bs[br][bc + 64] = b1;
    __syncthreads();
#pragma unroll
    for (int k = 0; k < 16; ++k) {
      const float4 av0 = *(const float4*)&As[k][ty << 3];
      const float4 av1 = *(const float4*)&As[k][(ty << 3) + 4];
      const float4 bv0 = *(const float4*)&Bs[k][tx << 3];
      const float4 bv1 = *(const float4*)&Bs[k][(tx << 3) + 4];
      const float a[8] = {av0.x, av0.y, av0.z, av0.w, av1.x, av1.y, av1.z, av1.w};
      const float b[8] = {bv0.x, bv0.y, bv0.z, bv0.w, bv1.x, bv1.y, bv1.z, bv1.w};
#pragma unroll
      for (int i = 0; i < 8; ++i)
#pragma unroll
        for (int j = 0; j < 8; ++j) acc[i][j] += a[i] * b[j];
    }
  }
#pragma unroll
  for (int i = 0; i < 8; ++i) {
    const size_t row = (size_t)(bm + (ty << 3) + i) * NG + bn + (tx << 3);
    float4 o0 = {acc[i][0], acc[i][1], acc[i][2], acc[i][3]};
    float4 o1 = {acc[i][4], acc[i][5], acc[i][6], acc[i][7]};
    *(float4*)&C[row]     = o0;
    *(float4*)&C[row + 4] = o1;
  }
}

// Persistent per-layer scan over a chunk of nsteps. Each block owns 2 batch rows;
// thread t owns hidden unit t (and gate columns 4t..4t+3 in the dot/LN phase).
// Running h/c state lives in hsl/csl (global), loaded at entry, stored at exit.
__global__ __launch_bounds__(256) void lstm_rec(
    const float* __restrict__ gx,     // [nsteps][B][NG] raw x-projection (chunk-local)
    const float* __restrict__ whl,    // [H][NG]
    float* __restrict__ hsl,          // [B][H] running h state (also final output slot)
    float* __restrict__ csl,          // [B][H] running c state (also final output slot)
    const float* __restrict__ gam,    // [2*NG] (gx gamma | gh gamma)
    const float* __restrict__ bet,    // [2*NG]
    const float* __restrict__ bias,   // [NG]
    float* __restrict__ ys,           // [S][B][H] full-sequence output
    int t0, int nsteps)
{
  __shared__ __align__(16) float hbuf[2][HH];
  __shared__ __align__(16) float gex[2][NG];
  __shared__ float red[4][8];

  const int tid = threadIdx.x;
  const int b0  = blockIdx.x * 2;
  const int lane = tid & 63;
  const int wid  = tid >> 6;

  // per-column constants (cols 4t..4t+3)
  const float4 gxg = *(const float4*)&gam[4 * tid];
  const float4 gxb = *(const float4*)&bet[4 * tid];
  const float4 ghg = *(const float4*)&gam[NG + 4 * tid];
  const float4 ghb = *(const float4*)&bet[NG + 4 * tid];
  const float4 bi  = *(const float4*)&bias[4 * tid];

  float c[2];
  c[0] = csl[(b0 + 0) * HH + tid];
  c[1] = csl[(b0 + 1) * HH + tid];
  hbuf[0][tid] = hsl[(b0 + 0) * HH + tid];
  hbuf[1][tid] = hsl[(b0 + 1) * HH + tid];
  __syncthreads();

  const float4* wh4 = (const float4*)whl;  // row stride NG/4 = 256 float4

  for (int t = 0; t < nsteps; ++t) {
    // ---- prefetch raw gx rows for this step (independent of the dot loop) ----
    const float4 x0 = *(const float4*)&gx[((size_t)t * BB + b0 + 0) * NG + 4 * tid];
    const float4 x1 = *(const float4*)&gx[((size_t)t * BB + b0 + 1) * NG + 4 * tid];

    // ---- gh = h @ wh for our 2 rows, cols 4t..4t+3 ----
    float4 a0 = {0, 0, 0, 0}, a1 = {0, 0, 0, 0};
#pragma unroll 8
    for (int k = 0; k < HH; k += 4) {
      float4 hv0 = *(const float4*)&hbuf[0][k];
      float4 hv1 = *(const float4*)&hbuf[1][k];
      float h0a[4] = {hv0.x, hv0.y, hv0.z, hv0.w};
      float h1a[4] = {hv1.x, hv1.y, hv1.z, hv1.w};
#pragma unroll
      for (int kk = 0; kk < 4; ++kk) {
        float4 w = wh4[(k + kk) * (NG / 4) + tid];
        a0.x += h0a[kk] * w.x; a0.y += h0a[kk] * w.y;
        a0.z += h0a[kk] * w.z; a0.w += h0a[kk] * w.w;
        a1.x += h1a[kk] * w.x; a1.y += h1a[kk] * w.y;
        a1.z += h1a[kk] * w.z; a1.w += h1a[kk] * w.w;
      }
    }

    // ---- block-wide LN stats: {sum,sumsq} x {gh0,gh1,gx0,gx1} ----
    float v[8] = {sum4(a0), sumsq4(a0), sum4(a1), sumsq4(a1),
                  sum4(x0), sumsq4(x0), sum4(x1), sumsq4(x1)};
#pragma unroll
    for (int off = 32; off; off >>= 1)
#pragma unroll
      for (int j = 0; j < 8; ++j) v[j] += __shfl_xor(v[j], off);
    if (lane == 0) {
#pragma unroll
      for (int j = 0; j < 8; ++j) red[wid][j] = v[j];
    }
    __syncthreads();
    float s[8];
#pragma unroll
    for (int j = 0; j < 8; ++j)
      s[j] = red[0][j] + red[1][j] + red[2][j] + red[3][j];

    const float inv = 1.0f / (float)NG;
    const float muh0 = s[0] * inv, muh1 = s[2] * inv;
    const float mux0 = s[4] * inv, mux1 = s[6] * inv;
    const float rsh0 = rsqrtf(s[1] * inv - muh0 * muh0 + EPSV);
    const float rsh1 = rsqrtf(s[3] * inv - muh1 * muh1 + EPSV);
    const float rsx0 = rsqrtf(s[5] * inv - mux0 * mux0 + EPSV);
    const float rsx1 = rsqrtf(s[7] * inv - mux1 * mux1 + EPSV);

    // ---- gate pre-activations for cols 4t..4t+3, both rows ----
    float4 g0, g1;
    g0.x = (x0.x - mux0) * rsx0 * gxg.x + gxb.x + (a0.x - muh0) * rsh0 * ghg.x + ghb.x + bi.x;
    g0.y = (x0.y - mux0) * rsx0 * gxg.y + gxb.y + (a0.y - muh0) * rsh0 * ghg.y + ghb.y + bi.y;
    g0.z = (x0.z - mux0) * rsx0 * gxg.z + gxb.z + (a0.z - muh0) * rsh0 * ghg.z + ghb.z + bi.z;
    g0.w = (x0.w - mux0) * rsx0 * gxg.w + gxb.w + (a0.w - muh0) * rsh0 * ghg.w + ghb.w + bi.w;
    g1.x = (x1.x - mux1) * rsx1 * gxg.x + gxb.x + (a1.x - muh1) * rsh1 * ghg.x + ghb.x + bi.x;
    g1.y = (x1.y - mux1) * rsx1 * gxg.y + gxb.y + (a1.y - muh1) * rsh1 * ghg.y + ghb.y + bi.y;
    g1.z = (x1.z - mux1) * rsx1 * gxg.z + gxb.z + (a1.z - muh1) * rsh1 * ghg.z + ghb.z + bi.z;
    g1.w = (x1.w - mux1) * rsx1 * gxg.w + gxb.w + (a1.w - muh1) * rsh1 * ghg.w + ghb.w + bi.w;

    *(float4*)&gex[0][4 * tid] = g0;
    *(float4*)&gex[1][4 * tid] = g1;
    __syncthreads();

    // ---- thread t gathers i,f,o,g for hidden unit t and updates state ----
#pragma unroll
    for (int r = 0; r < 2; ++r) {
      const float gi = gex[r][tid];
      const float gf = gex[r][256 + tid];
      const float go = gex[r][512 + tid];
      const float gg = gex[r][768 + tid];
      const float ii = fast_sigmoid(gi);
      const float ff = fast_sigmoid(gf);
      const float oo = fast_sigmoid(go);
      const float g  = fast_tanh(gg);
      const float cn = ff * c[r] + ii * g;
      const float hn = oo * fast_tanh(cn);
      c[r] = cn;
      hbuf[r][tid] = hn;
      ys[((size_t)(t0 + t) * BB + b0 + r) * HH + tid] = hn;
    }
    __syncthreads();  // hbuf ready for next step
  }

  // write back running state (after last chunk this IS the hT/cT output)
  hsl[(b0 + 0) * HH + tid] = hbuf[0][tid];
  hsl[(b0 + 1) * HH + tid] = hbuf[1][tid];
  csl[(b0 + 0) * HH + tid] = c[0];
  csl[(b0 + 1) * HH + tid] = c[1];
}

extern "C" void kernel_launch(void* const* d_in, const int* in_sizes, int n_in,
                              void* d_out, int out_size, void* d_ws, size_t ws_size,
                              hipStream_t stream) {
  const float* x    = (const float*)d_in[0];
  const float* h0   = (const float*)d_in[1];
  const float* c0   = (const float*)d_in[2];
  const float* wx   = (const float*)d_in[3];
  const float* wh   = (const float*)d_in[4];
  const float* bias = (const float*)d_in[5];
  const float* gam  = (const float*)d_in[6];
  const float* bet  = (const float*)d_in[7];

  float* out  = (float*)d_out;
  float* ys_x = out;                                  // [S][B][H]: ys0 scratch, then final x
  float* hs   = out + (size_t)SS * BB * HH;           // [L][B][H] (doubles as running h state)
  float* cs   = hs + (size_t)NL * BB * HH;            // [L][B][H] (doubles as running c state)
  float* gxbuf = (float*)d_ws;                        // up to [S][B][NG] = 128 MiB

  // chunk the time axis to whatever the workspace can hold
  const size_t step_bytes = (size_t)BB * NG * sizeof(float);
  int T = (int)(ws_size / step_bytes);
  if (T > SS) T = SS;
  if (T < 1)  T = 1;

  const int nstate = NL * BB * HH;
  init_state<<<(nstate + 255) / 256, 256, 0, stream>>>(h0, c0, hs, cs, nstate);

  for (int l = 0; l < NL; ++l) {
    const float* Ain = (l == 0) ? x : ys_x;
    for (int t0 = 0; t0 < SS; t0 += T) {
      const int nt = (SS - t0 < T) ? (SS - t0) : T;
      const dim3 ggrid(NG / 128, nt);   // M = nt*BB rows, 128 rows/block
      gemm_gx<<<ggrid, 256, 0, stream>>>(Ain + (size_t)t0 * BB * INN,
                                         wx + (size_t)l * INN * NG, gxbuf);
      lstm_rec<<<BB / 2, 256, 0, stream>>>(
          gxbuf, wh + (size_t)l * HH * NG,
          hs + (size_t)l * BB * HH, cs + (size_t)l * BB * HH,
          gam + (size_t)l * 2 * NG, bet + (size_t)l * 2 * NG,
          bias + (size_t)l * NG, ys_x, t0, nt);
    }
  }
}